// Round 8
// baseline (22.705 us; speedup 1.0000x reference)
//
#include <hip/hip_runtime.h>

#define V 10
#define L 45            // V*(V-1)/2
#define NCOEF 14
#define NSAMP 65536
#define NTHR 256
#define NBLK 2048       // full machine: 8 blocks/CU x 256 CU

typedef float v4f __attribute__((ext_vector_type(4)));

__global__ __launch_bounds__(NTHR) void decor_stream(
    const float* __restrict__ x, const float* __restrict__ log_d,
    const float* __restrict__ params,
    float* __restrict__ out, float* __restrict__ Mout, float* __restrict__ logd_out,
    float* __restrict__ scal)
{
    __shared__ float ps[NCOEF * L];      // 2.52 KB
    const int tid  = threadIdx.x;
    const int lane = tid & 63;

    // Wave-redundant params staging: every wave writes the full array with its
    // own 64 lanes, so no __syncthreads is needed — a wave only reads entries
    // it wrote itself; other waves' racing writes carry identical values.
    for (int idx = lane; idx < NCOEF * L; idx += 64)
        ps[idx] = params[idx];

    const float c16 = 1.0f / 6.0f;

    // ---- ridge scalars: block 0 / wave 0, before the streaming loop ----
    if (blockIdx.x == 0 && tid < 64) {
        float s_par = 0.f, s_fir = 0.f, s_sec = 0.f;
        for (int idx = lane; idx < NCOEF * L; idx += 64) {
            int k = idx / L;
            float p0 = ps[idx];
            s_par += p0 * p0;
            if (k + 1 < NCOEF) {
                float p1 = ps[idx + L];
                float d1 = p1 - p0;
                s_fir += d1 * d1;
                if (k + 2 < NCOEF) {
                    float p2 = ps[idx + 2 * L];
                    float d2 = p2 - 2.f * p1 + p0;
                    s_sec += d2 * d2;
                }
            }
        }
        for (int off = 32; off; off >>= 1) {
            s_sec += __shfl_down(s_sec, off);
            s_fir += __shfl_down(s_fir, off);
            s_par += __shfl_down(s_par, off);
        }
        if (lane == 0) { scal[0] = s_sec; scal[1] = s_fir; scal[2] = s_par; }
    }

    // ---- barrier-free grid-stride stream over three ranges ----
    const size_t NM4  = (size_t)NSAMP * 25;        // M float4 units
    const size_t NLD4 = (size_t)NSAMP * V / 4;     // log_d float4 units
    const size_t NTOT = NM4 + NLD4 + NSAMP;        // + out sample-row units

    for (size_t u = (size_t)blockIdx.x * NTHR + tid; u < NTOT;
         u += (size_t)NBLK * NTHR) {
        if (u < NM4) {
            // ---- one float4 of M (coalesced nt store) ----
            size_t n = u / 25;
            int q  = (int)(u - n * 25);
            int e0 = q * 4;
            const float* xr = x + n * V;
            v4f v;
            #pragma unroll
            for (int t = 0; t < 4; ++t) {
                int ee = e0 + t;
                int i  = (ee * 205) >> 11;     // ee/10 for ee<100
                int j  = ee - 10 * i;
                float val;
                if (j > i)       val = 0.0f;
                else if (j == i) val = 1.0f;
                else {
                    float xv = fminf(fmaxf(xr[j], -5.0f), 5.0f);
                    float uu = (xv + 5.0f) * 1.1f + 3.0f;
                    int   ii = (int)floorf(uu);
                    ii = max(3, min(ii, 14));      // ref: x=+5 lands in [t14,t15)
                    float f  = uu - (float)ii;
                    float omf = 1.0f - f;
                    float f2 = f * f, f3 = f2 * f;
                    float N0 = omf * omf * omf * c16;
                    float N1 = (3.f * f3 - 6.f * f2 + 4.f) * c16;
                    float N2 = (-3.f * f3 + 3.f * f2 + 3.f * f + 1.f) * c16;
                    float N3 = f3 * c16;           // == 0 when ii==14
                    int b  = (ii - 3) * L;
                    int b3 = min(b + 3 * L, 13 * L);  // B_14 dropped by ref; N3==0 there
                    int l  = (i * (i - 1)) / 2 + j;
                    val = N0 * ps[b + l] + N1 * ps[b + L + l]
                        + N2 * ps[b + 2 * L + l] + N3 * ps[b3 + l];
                }
                v[t] = val;
            }
            __builtin_nontemporal_store(v, (v4f*)Mout + u);
        } else if (u < NM4 + NLD4) {
            // ---- log_d passthrough (float4 nt copy) ----
            size_t w = u - NM4;
            __builtin_nontemporal_store(
                __builtin_nontemporal_load((const v4f*)log_d + w),
                (v4f*)logd_out + w);
        } else {
            // ---- one sample's out row, fully in registers (lane-owned) ----
            size_t n = u - NM4 - NLD4;
            const float* xr = x + n * V;
            float xv[V], acc[V];
            #pragma unroll
            for (int j = 0; j < V; ++j) { xv[j] = xr[j]; acc[j] = xv[j]; }
            #pragma unroll
            for (int j = 0; j < V - 1; ++j) {
                float xc = fminf(fmaxf(xv[j], -5.0f), 5.0f);
                float uu = (xc + 5.0f) * 1.1f + 3.0f;
                int   ii = (int)floorf(uu);
                ii = max(3, min(ii, 14));
                float f  = uu - (float)ii;
                float omf = 1.0f - f;
                float f2 = f * f, f3 = f2 * f;
                float N0 = omf * omf * omf * c16;
                float N1 = (3.f * f3 - 6.f * f2 + 4.f) * c16;
                float N2 = (-3.f * f3 + 3.f * f2 + 3.f * f + 1.f) * c16;
                float N3 = f3 * c16;
                int b  = (ii - 3) * L;
                int b3 = min(b + 3 * L, 13 * L);
                #pragma unroll
                for (int i = j + 1; i < V; ++i) {
                    int l = (i * (i - 1)) / 2 + j;
                    float lam = N0 * ps[b + l] + N1 * ps[b + L + l]
                              + N2 * ps[b + 2 * L + l] + N3 * ps[b3 + l];
                    acc[i] += lam * xv[j];
                }
            }
            float* orow = out + n * V;
            #pragma unroll
            for (int i = 0; i < V; ++i) orow[i] = acc[i];
        }
    }
}

extern "C" void kernel_launch(void* const* d_in, const int* in_sizes, int n_in,
                              void* d_out, int out_size, void* d_ws, size_t ws_size,
                              hipStream_t stream) {
    const float* x      = (const float*)d_in[0];
    const float* log_d  = (const float*)d_in[1];
    const float* params = (const float*)d_in[2];

    float* out      = (float*)d_out;                       // [N, V]
    float* M        = out + (size_t)NSAMP * V;             // [N, V, V]
    float* logd_out = M + (size_t)NSAMP * V * V;           // [N, V]
    float* scal     = logd_out + (size_t)NSAMP * V;        // sec, fir, par

    decor_stream<<<NBLK, NTHR, 0, stream>>>(x, log_d, params, out, M, logd_out, scal);
}

// Round 9
// 17.670 us; speedup vs baseline: 1.2849x; 1.2849x over previous
//
#include <hip/hip_runtime.h>

#define V 10
#define L 45            // V*(V-1)/2
#define NCOEF 14
#define NSAMP 65536
#define BS 32           // samples per block
#define NTHR 256        // 4 waves -> 8 blocks/CU = 32 waves/CU (full occupancy)
#define LAMP 46         // padded lam row stride

typedef float v4f __attribute__((ext_vector_type(4)));

// col index j for pair l (tril_indices(V, k=-1) row-major order)
__constant__ unsigned char c_col[L] = {
    0,
    0,1,
    0,1,2,
    0,1,2,3,
    0,1,2,3,4,
    0,1,2,3,4,5,
    0,1,2,3,4,5,6,
    0,1,2,3,4,5,6,7,
    0,1,2,3,4,5,6,7,8
};

__global__ __launch_bounds__(NTHR, 8) void decor_fused(
    const float* __restrict__ x, const float* __restrict__ log_d,
    const float* __restrict__ params,
    float* __restrict__ out, float* __restrict__ Mout, float* __restrict__ logd_out,
    float* __restrict__ scal)
{
    __shared__ float ps[NCOEF * L];          // 2.52 KB
    __shared__ float xs[BS * V];             // 1.28 KB
    __shared__ float lam[BS * LAMP];         // 5.89 KB
    __shared__ unsigned char cols[64];

    const int tid = threadIdx.x;
    const int n0  = blockIdx.x * BS;

    // ---- stage params + cols + x tile into LDS (coalesced) ----
    for (int idx = tid; idx < NCOEF * L; idx += NTHR)
        ps[idx] = params[idx];
    if (tid < L) cols[tid] = c_col[tid];
    const v4f* x4 = (const v4f*)(x + (size_t)n0 * V);
    for (int idx = tid; idx < BS * V / 4; idx += NTHR)
        ((v4f*)xs)[idx] = __builtin_nontemporal_load(&x4[idx]);

    // ---- log_d passthrough (nt float4 copy) ----
    const v4f* ld4  = (const v4f*)(log_d + (size_t)n0 * V);
    v4f*       ldo4 = (v4f*)(logd_out + (size_t)n0 * V);
    for (int idx = tid; idx < BS * V / 4; idx += NTHR)
        __builtin_nontemporal_store(__builtin_nontemporal_load(&ld4[idx]), &ldo4[idx]);

    __syncthreads();

    // ---- lambdas: BS*L = 1440 evals, params gathered from LDS ----
    // uniform knots, spacing d = 10/11; u = (x+5)/d + 3
    const float inv_d = 1.1f;
    const float c16   = 1.0f / 6.0f;
    for (int idx = tid; idx < BS * L; idx += NTHR) {
        int nl = idx / L;
        int l  = idx - nl * L;
        float xv = xs[nl * V + cols[l]];
        xv = fminf(fmaxf(xv, -5.0f), 5.0f);
        float u  = (xv + 5.0f) * inv_d + 3.0f;
        int   ii = (int)floorf(u);
        ii = max(3, min(ii, 14));          // ref indicator: x=+5 lands in [t14,t15)
        float f  = u - (float)ii;
        float omf = 1.0f - f;
        float f2 = f * f, f3 = f2 * f;
        float N0 = omf * omf * omf * c16;
        float N1 = (3.0f * f3 - 6.0f * f2 + 4.0f) * c16;
        float N2 = (-3.0f * f3 + 3.0f * f2 + 3.0f * f + 1.0f) * c16;
        float N3 = f3 * c16;               // == 0 when ii==14
        int k0 = ii - 3;
        int k3 = min(k0 + 3, NCOEF - 1);   // B_14 dropped by ref; N3==0 there
        lam[nl * LAMP + l] =
              N0 * ps[(k0    ) * L + l]
            + N1 * ps[(k0 + 1) * L + l]
            + N2 * ps[(k0 + 2) * L + l]
            + N3 * ps[(k3    ) * L + l];
    }
    __syncthreads();

    // ---- assemble + store M (float4, nt) from lam ----
    v4f* M4 = (v4f*)(Mout + (size_t)n0 * V * V);
    for (int idx = tid; idx < BS * 25; idx += NTHR) {
        int nl = idx / 25;
        int q  = idx - nl * 25;
        int e0 = q * 4;
        const float* lr = &lam[nl * LAMP];
        v4f v;
        #pragma unroll
        for (int t = 0; t < 4; ++t) {
            int ee = e0 + t;
            int i  = (ee * 205) >> 11;     // ee/10 for ee<100
            int j  = ee - 10 * i;
            float val;
            if (j > i)       val = 0.0f;
            else if (j == i) val = 1.0f;
            else             val = lr[(i * (i - 1)) / 2 + j];
            v[t] = val;
        }
        __builtin_nontemporal_store(v, &M4[idx]);
    }

    // ---- out = M @ x (strict-lower + identity), direct coalesced stores ----
    for (int idx = tid; idx < BS * V; idx += NTHR) {
        int nl = idx / V;
        int i  = idx - nl * V;
        float acc = xs[idx];
        const float* lr = &lam[nl * LAMP + (i * (i - 1)) / 2];
        for (int j = 0; j < i; ++j)
            acc += lr[j] * xs[nl * V + j];
        __builtin_nontemporal_store(acc, &out[(size_t)n0 * V + idx]);
    }

    // ---- ridge scalars: one wave of block 0, params from LDS ----
    if (blockIdx.x == 0 && tid < 64) {
        float s_par = 0.f, s_fir = 0.f, s_sec = 0.f;
        for (int idx = tid; idx < NCOEF * L; idx += 64) {
            int k = idx / L;
            float p0 = ps[idx];
            s_par += p0 * p0;
            if (k + 1 < NCOEF) {
                float p1 = ps[idx + L];
                float d1 = p1 - p0;
                s_fir += d1 * d1;
                if (k + 2 < NCOEF) {
                    float p2 = ps[idx + 2 * L];
                    float d2 = p2 - 2.f * p1 + p0;
                    s_sec += d2 * d2;
                }
            }
        }
        for (int off = 32; off; off >>= 1) {
            s_sec += __shfl_down(s_sec, off);
            s_fir += __shfl_down(s_fir, off);
            s_par += __shfl_down(s_par, off);
        }
        if (tid == 0) { scal[0] = s_sec; scal[1] = s_fir; scal[2] = s_par; }
    }
}

extern "C" void kernel_launch(void* const* d_in, const int* in_sizes, int n_in,
                              void* d_out, int out_size, void* d_ws, size_t ws_size,
                              hipStream_t stream) {
    const float* x      = (const float*)d_in[0];
    const float* log_d  = (const float*)d_in[1];
    const float* params = (const float*)d_in[2];

    float* out      = (float*)d_out;                       // [N, V]
    float* M        = out + (size_t)NSAMP * V;             // [N, V, V]
    float* logd_out = M + (size_t)NSAMP * V * V;           // [N, V]
    float* scal     = logd_out + (size_t)NSAMP * V;        // sec, fir, par

    decor_fused<<<NSAMP / BS, NTHR, 0, stream>>>(x, log_d, params, out, M, logd_out, scal);
}